// Round 15
// baseline (246.943 us; speedup 1.0000x reference)
//
#include <hip/hip_runtime.h>
#include <hip/hip_bf16.h>
#include <stdint.h>

#define N_TOK 8192
#define DDIM 1024
#define FDIM 4096
#define NEXP 8

typedef __attribute__((ext_vector_type(8))) short short8;
typedef __attribute__((ext_vector_type(4))) float f32x4;

__device__ __forceinline__ ushort f2bf(float f) {
  uint32_t u = __float_as_uint(f);
  u += 0x7FFF + ((u >> 16) & 1);   // RNE
  return (ushort)(u >> 16);
}

__device__ __forceinline__ void gload16(const void* g, void* l) {
  __builtin_amdgcn_global_load_lds((const __attribute__((address_space(1))) void*)g,
                                   (__attribute__((address_space(3))) void*)l, 16, 0, 0);
}

// ---------- prep (R13 proven) ----------
__global__ __launch_bounds__(256) void prep_kernel(
    const float* __restrict__ wi, ushort* __restrict__ wib,
    const float* __restrict__ x, const float* __restrict__ gW, const float* __restrict__ gb,
    const float* __restrict__ lA, const float* __restrict__ lB,
    ushort* __restrict__ Pmat, ushort* __restrict__ BcatB,
    ushort* __restrict__ xb) {
  if (blockIdx.x < 4096) {
    int i = blockIdx.x * 256 + threadIdx.x;
    float4 v = reinterpret_cast<const float4*>(wi)[i];
    ushort4 o;
    o.x = f2bf(v.x); o.y = f2bf(v.y); o.z = f2bf(v.z); o.w = f2bf(v.w);
    reinterpret_cast<ushort4*>(wib)[i] = o;
    return;
  }
  const int rblk = blockIdx.x - 4096;              // [0, 2048)
  if (threadIdx.x < 16) {
    int idx = rblk * 64 + threadIdx.x * 4;
    int f = idx >> 5;
    int e = (idx & 31) >> 2;
    const float* src = lB + ((size_t)e * FDIM + f) * 4;
    ushort4 o;
    o.x = f2bf(src[0]); o.y = f2bf(src[1]); o.z = f2bf(src[2]); o.w = f2bf(src[3]);
    *reinterpret_cast<ushort4*>(BcatB + idx) = o;
  }
  const int lane = threadIdx.x & 63;
  const int wid = threadIdx.x >> 6;
  const int tok = rblk * 4 + wid;
  const float* xp = x + (size_t)tok * DDIM;
  float4 xv[4];
#pragma unroll
  for (int i = 0; i < 4; ++i)
    xv[i] = *reinterpret_cast<const float4*>(xp + i * 256 + lane * 4);
#pragma unroll
  for (int i = 0; i < 4; ++i) {
    ushort4 o;
    o.x = f2bf(xv[i].x); o.y = f2bf(xv[i].y); o.z = f2bf(xv[i].z); o.w = f2bf(xv[i].w);
    *reinterpret_cast<ushort4*>(xb + (size_t)tok * DDIM + i * 256 + lane * 4) = o;
  }
  double lg[NEXP];
#pragma unroll
  for (int e = 0; e < NEXP; ++e) {
    const float* gp = gW + e * DDIM;
    double s = 0.0;
#pragma unroll
    for (int i = 0; i < 4; ++i) {
      float4 g = *reinterpret_cast<const float4*>(gp + i * 256 + lane * 4);
      s += (double)xv[i].x * g.x + (double)xv[i].y * g.y +
           (double)xv[i].z * g.z + (double)xv[i].w * g.w;
    }
    lg[e] = s;
  }
#pragma unroll
  for (int e = 0; e < NEXP; ++e)
    for (int off = 32; off > 0; off >>= 1) lg[e] += __shfl_xor(lg[e], off);
  int best = 0;
  double bv = lg[0] + (double)gb[0];
#pragma unroll
  for (int e = 1; e < NEXP; ++e) {
    double v = lg[e] + (double)gb[e];
    if (v > bv) { bv = v; best = e; }
  }
  float c[4];
#pragma unroll
  for (int r = 0; r < 4; ++r) {
    const float* ap = lA + ((size_t)best * 4 + r) * DDIM;
    float s = 0.f;
#pragma unroll
    for (int i = 0; i < 4; ++i) {
      float4 a = *reinterpret_cast<const float4*>(ap + i * 256 + lane * 4);
      s = fmaf(xv[i].x, a.x, s); s = fmaf(xv[i].y, a.y, s);
      s = fmaf(xv[i].z, a.z, s); s = fmaf(xv[i].w, a.w, s);
    }
    for (int off = 32; off > 0; off >>= 1) s += __shfl_xor(s, off);
    c[r] = s;
  }
  if (lane < 32) {
    int r = lane & 3;
    float cv = (r == 0) ? c[0] : (r == 1) ? c[1] : (r == 2) ? c[2] : c[3];
    float pv = ((lane >> 2) == best) ? cv : 0.f;
    Pmat[(size_t)tok * 32 + lane] = f2bf(pv);
  }
}

// =====================================================================
// GEMM1: inter = relu(xb @ wiWb^T + Pmat @ Bcat^T + wi_b)
// R14 quad-tile structure, LDS switched to CHUNK-MAJOR [kchunk][128][8]
// (zero bank conflicts: each 16-lane group reads a contiguous 256B run).
// Regions (ushort offs): A.k0 [0,4K) A.k1 [4K,8K) B.k0 [8K,12K) B.k1 [12K,16K).
// Staging: thread (rs=tid&127, ch=tid>>7) writes chunks ch & ch+2 per k-half;
// dest = tid*8 (+2048 for the second chunk) -- linear, gload_lds-compatible.
// =====================================================================
__global__ __launch_bounds__(256) void gemm1_kernel(
    const ushort* __restrict__ A, const ushort* __restrict__ Ap,
    const ushort* __restrict__ B, const ushort* __restrict__ Bc,
    const float* __restrict__ bias,
    const float* __restrict__ wo, ushort* __restrict__ wob,
    ushort* __restrict__ C) {
  __shared__ __align__(16) ushort lds[16384];   // 32 KB
  const int tid = threadIdx.x;
  const int lane = tid & 63;
  const int wid = tid >> 6;
  const int wr = wid >> 1, wc = wid & 1;        // 2x2 waves, each 64x64
  const int brow = blockIdx.x;                  // 64
  const int bcolg = blockIdx.y;                 // 8

  // ---- folded wo cast: this block's 8192-elem slice ----
  {
    const size_t base = (size_t)(brow * 8 + bcolg) * 8192 + tid * 8;
#pragma unroll
    for (int c = 0; c < 4; ++c) {
      const size_t off = base + c * 2048;
      float4 v0 = *reinterpret_cast<const float4*>(wo + off);
      float4 v1 = *reinterpret_cast<const float4*>(wo + off + 4);
      ushort4 o0, o1;
      o0.x = f2bf(v0.x); o0.y = f2bf(v0.y); o0.z = f2bf(v0.z); o0.w = f2bf(v0.w);
      o1.x = f2bf(v1.x); o1.y = f2bf(v1.y); o1.z = f2bf(v1.z); o1.w = f2bf(v1.w);
      *reinterpret_cast<ushort4*>(wob + off) = o0;
      *reinterpret_cast<ushort4*>(wob + off + 4) = o1;
    }
  }

  // chunk-major staging ids
  const int rs = tid & 127, ch = tid >> 7;      // row, first chunk
  const ushort* gA = A + (size_t)(brow * 128 + rs) * DDIM + ch * 8;
  const ushort* gP = Ap + (size_t)(brow * 128 + rs) * 32 + ch * 8;
  ushort* const d0 = lds + tid * 8;             // = ch*1024 + rs*8

  // chunk-major read offsets: group g reads chunk g (contiguous 256B/group)
  const int g = lane >> 4, rlo = lane & 15;
  const int aoff = g * 1024 + (wr * 64 + rlo) * 8;            // + m*128; k-half1: +4096
  const int boff = 8192 + g * 1024 + (wc * 64 + rlo) * 8;     // + n*128; k-half1: +4096
  const int ccb = wc * 64 + (lane & 15);

#pragma unroll 1
  for (int t4 = 0; t4 < 4; ++t4) {
    const int bcol = bcolg * 4 + t4;
    const ushort* gB = B + (size_t)(bcol * 128 + rs) * DDIM + ch * 8;
    const ushort* gQ = Bc + (size_t)(bcol * 128 + rs) * 32 + ch * 8;

    f32x4 acc[4][4] = {};
    __syncthreads();   // LDS safe to overwrite (prev tile's reads done)

    for (int k0 = 0; k0 < DDIM; k0 += 64) {
      // k-half 0: A chunks {ch, ch+2} -> [0,4K); B -> [8K,12K)
      gload16(gA + k0,      d0);           gload16(gA + k0 + 16, d0 + 2048);
      gload16(gB + k0,      d0 + 8192);    gload16(gB + k0 + 16, d0 + 8192 + 2048);
      // k-half 1 (cols +32): A -> [4K,8K); B -> [12K,16K)
      gload16(gA + k0 + 32, d0 + 4096);    gload16(gA + k0 + 48, d0 + 4096 + 2048);
      gload16(gB + k0 + 32, d0 + 12288);   gload16(gB + k0 + 48, d0 + 12288 + 2048);
      __syncthreads();
      short8 af[4], bf[4];
#pragma unroll
      for (int m = 0; m < 4; ++m)
        af[m] = *reinterpret_cast<const short8*>(lds + aoff + m * 128);
#pragma unroll
      for (int n = 0; n < 4; ++n)
        bf[n] = *reinterpret_cast<const short8*>(lds + boff + n * 128);
#pragma unroll
      for (int n = 0; n < 4; ++n)
#pragma unroll
        for (int m = 0; m < 4; ++m)
          acc[m][n] = __builtin_amdgcn_mfma_f32_16x16x32_bf16(af[m], bf[n], acc[m][n], 0, 0, 0);
#pragma unroll
      for (int m = 0; m < 4; ++m)
        af[m] = *reinterpret_cast<const short8*>(lds + 4096 + aoff + m * 128);
#pragma unroll
      for (int n = 0; n < 4; ++n)
        bf[n] = *reinterpret_cast<const short8*>(lds + 4096 + boff + n * 128);
#pragma unroll
      for (int n = 0; n < 4; ++n)
#pragma unroll
        for (int m = 0; m < 4; ++m)
          acc[m][n] = __builtin_amdgcn_mfma_f32_16x16x32_bf16(af[m], bf[n], acc[m][n], 0, 0, 0);
      __syncthreads();
    }

    // ---- lora fold: BK=32 over P [8192][32] x Bcat [4096][32] ----
    {
      gload16(gP,      d0);           gload16(gP + 16, d0 + 2048);
      gload16(gQ,      d0 + 8192);    gload16(gQ + 16, d0 + 8192 + 2048);
      __syncthreads();
      short8 af[4], bf[4];
#pragma unroll
      for (int m = 0; m < 4; ++m)
        af[m] = *reinterpret_cast<const short8*>(lds + aoff + m * 128);
#pragma unroll
      for (int n = 0; n < 4; ++n)
        bf[n] = *reinterpret_cast<const short8*>(lds + boff + n * 128);
#pragma unroll
      for (int n = 0; n < 4; ++n)
#pragma unroll
        for (int m = 0; m < 4; ++m)
          acc[m][n] = __builtin_amdgcn_mfma_f32_16x16x32_bf16(af[m], bf[n], acc[m][n], 0, 0, 0);
    }

    // ---- epilogue: bias + relu + bf16 store ----
    float bias4[4];
#pragma unroll
    for (int fn = 0; fn < 4; ++fn) bias4[fn] = bias[bcol * 128 + ccb + fn * 16];
#pragma unroll
    for (int fm = 0; fm < 4; ++fm) {
#pragma unroll
      for (int q = 0; q < 4; ++q) {
        const int tl = wr * 64 + fm * 16 + ((lane >> 4) << 2) + q;
        ushort* crow = C + (size_t)(brow * 128 + tl) * FDIM + bcol * 128;
#pragma unroll
        for (int fn = 0; fn < 4; ++fn) {
          float v = acc[fm][fn][q] + bias4[fn];
          crow[ccb + fn * 16] = f2bf(fmaxf(v, 0.f));
        }
      }
    }
  }
}

// =====================================================================
// GEMM2 (round-10 proven, ~69us): out = inter @ woWb^T + wo_b  (f32)
// m97 128x128 + BK=64 unroll-by-2. UNCHANGED.
// =====================================================================
__global__ __launch_bounds__(256) void gemm2_kernel(
    const ushort* __restrict__ A, const ushort* __restrict__ B,
    const float* __restrict__ bias, float* __restrict__ C) {
  __shared__ __align__(16) ushort lds[16384];   // 32 KB
  const int tid = threadIdx.x;
  const int lane = tid & 63;
  const int wid = tid >> 6;
  const int wr = wid >> 1, wc = wid & 1;
  const int brow = blockIdx.x, bcol = blockIdx.y;

  f32x4 acc[4][4] = {};

  const int srow = tid >> 2;
  const int scol = (tid & 3) * 8;
  const ushort* gA0 = A + (size_t)(brow * 128 + srow) * FDIM + scol;
  const ushort* gA1 = A + (size_t)(brow * 128 + 64 + srow) * FDIM + scol;
  const ushort* gB0 = B + (size_t)(bcol * 128 + srow) * FDIM + scol;
  const ushort* gB1 = B + (size_t)(bcol * 128 + 64 + srow) * FDIM + scol;
  ushort* const d0 = lds + tid * 8;

  const int offA = (wr * 64 + (lane & 15)) * 32 + (lane >> 4) * 8;
  const int offB = 8192 + (wc * 64 + (lane & 15)) * 32 + (lane >> 4) * 8;

  for (int k0 = 0; k0 < FDIM; k0 += 64) {
    gload16(gA0 + k0, d0);          gload16(gA1 + k0, d0 + 2048);
    gload16(gB0 + k0, d0 + 8192);   gload16(gB1 + k0, d0 + 8192 + 2048);
    gload16(gA0 + k0 + 32, d0 + 4096);          gload16(gA1 + k0 + 32, d0 + 4096 + 2048);
    gload16(gB0 + k0 + 32, d0 + 12288);         gload16(gB1 + k0 + 32, d0 + 12288 + 2048);
    __syncthreads();
    short8 af[4], bf[4];
#pragma unroll
    for (int m = 0; m < 4; ++m)
      af[m] = *reinterpret_cast<const short8*>(lds + offA + m * 512);
#pragma unroll
    for (int n = 0; n < 4; ++n)
      bf[n] = *reinterpret_cast<const short8*>(lds + offB + n * 512);
#pragma unroll
    for (int n = 0; n < 4; ++n)
#pragma unroll
      for (int m = 0; m < 4; ++m)
        acc[m][n] = __builtin_amdgcn_mfma_f32_16x16x32_bf16(af[m], bf[n], acc[m][n], 0, 0, 0);
#pragma unroll
    for (int m = 0; m < 4; ++m)
      af[m] = *reinterpret_cast<const short8*>(lds + 4096 + offA + m * 512);
#pragma unroll
    for (int n = 0; n < 4; ++n)
      bf[n] = *reinterpret_cast<const short8*>(lds + 4096 + offB + n * 512);
#pragma unroll
    for (int n = 0; n < 4; ++n)
#pragma unroll
      for (int m = 0; m < 4; ++m)
        acc[m][n] = __builtin_amdgcn_mfma_f32_16x16x32_bf16(af[m], bf[n], acc[m][n], 0, 0, 0);
    __syncthreads();
  }

  const int dbase = bcol * 128 + wc * 64 + (lane & 15);
  const int tokbase = brow * 128 + wr * 64 + ((lane >> 4) << 2);
  float bias4[4];
#pragma unroll
  for (int n = 0; n < 4; ++n) bias4[n] = bias[dbase + n * 16];
#pragma unroll
  for (int m = 0; m < 4; ++m) {
#pragma unroll
    for (int q = 0; q < 4; ++q) {
      const int tok = tokbase + m * 16 + q;
#pragma unroll
      for (int n = 0; n < 4; ++n)
        C[(size_t)tok * DDIM + dbase + n * 16] = acc[m][n][q] + bias4[n];
    }
  }
}

extern "C" void kernel_launch(void* const* d_in, const int* in_sizes, int n_in,
                              void* d_out, int out_size, void* d_ws, size_t ws_size,
                              hipStream_t stream) {
  const float* x      = (const float*)d_in[0];
  const float* gate_W = (const float*)d_in[1];
  const float* gate_b = (const float*)d_in[2];
  const float* wi_W   = (const float*)d_in[3];
  const float* wi_b   = (const float*)d_in[4];
  const float* wo_W   = (const float*)d_in[5];
  const float* wo_b   = (const float*)d_in[6];
  const float* lora_A = (const float*)d_in[7];
  const float* lora_B = (const float*)d_in[8];
  float* out = (float*)d_out;

  char* ws = (char*)d_ws;
  ushort* xb    = (ushort*)(ws);                       // 16.78 MB
  ushort* wiWb  = (ushort*)(ws + 16777216);            //  8.39 MB
  ushort* woWb  = (ushort*)(ws + 25165824);            //  8.39 MB
  ushort* inter = (ushort*)(ws + 33554432);            // 67.1  MB
  ushort* Pmat  = (ushort*)(ws + 100663296);           // 512 KB
  ushort* BcatB = (ushort*)(ws + 101187584);           // 256 KB

  prep_kernel<<<6144, 256, 0, stream>>>(wi_W, wiWb,
                                        x, gate_W, gate_b, lora_A, lora_B,
                                        Pmat, BcatB, xb);
  gemm1_kernel<<<dim3(64, 8), 256, 0, stream>>>(
      xb, Pmat, wiWb, BcatB, wi_b, wo_W, woWb, inter);
  gemm2_kernel<<<dim3(N_TOK / 128, DDIM / 128), 256, 0, stream>>>(inter, woWb, wo_b, out);
}

// Round 16
// 190.700 us; speedup vs baseline: 1.2949x; 1.2949x over previous
//
#include <hip/hip_runtime.h>
#include <hip/hip_bf16.h>
#include <stdint.h>

#define N_TOK 8192
#define DDIM 1024
#define FDIM 4096
#define NEXP 8

typedef __attribute__((ext_vector_type(8))) short short8;
typedef __attribute__((ext_vector_type(4))) float f32x4;

__device__ __forceinline__ ushort f2bf(float f) {
  uint32_t u = __float_as_uint(f);
  u += 0x7FFF + ((u >> 16) & 1);   // RNE
  return (ushort)(u >> 16);
}

__device__ __forceinline__ void gload16(const void* g, void* l) {
  __builtin_amdgcn_global_load_lds((const __attribute__((address_space(1))) void*)g,
                                   (__attribute__((address_space(3))) void*)l, 16, 0, 0);
}

// ---------- prep (R13 proven) ----------
__global__ __launch_bounds__(256) void prep_kernel(
    const float* __restrict__ wi, ushort* __restrict__ wib,
    const float* __restrict__ x, const float* __restrict__ gW, const float* __restrict__ gb,
    const float* __restrict__ lA, const float* __restrict__ lB,
    ushort* __restrict__ Pmat, ushort* __restrict__ BcatB,
    ushort* __restrict__ xb) {
  if (blockIdx.x < 4096) {
    int i = blockIdx.x * 256 + threadIdx.x;
    float4 v = reinterpret_cast<const float4*>(wi)[i];
    ushort4 o;
    o.x = f2bf(v.x); o.y = f2bf(v.y); o.z = f2bf(v.z); o.w = f2bf(v.w);
    reinterpret_cast<ushort4*>(wib)[i] = o;
    return;
  }
  const int rblk = blockIdx.x - 4096;              // [0, 2048)
  if (threadIdx.x < 16) {
    int idx = rblk * 64 + threadIdx.x * 4;
    int f = idx >> 5;
    int e = (idx & 31) >> 2;
    const float* src = lB + ((size_t)e * FDIM + f) * 4;
    ushort4 o;
    o.x = f2bf(src[0]); o.y = f2bf(src[1]); o.z = f2bf(src[2]); o.w = f2bf(src[3]);
    *reinterpret_cast<ushort4*>(BcatB + idx) = o;
  }
  const int lane = threadIdx.x & 63;
  const int wid = threadIdx.x >> 6;
  const int tok = rblk * 4 + wid;
  const float* xp = x + (size_t)tok * DDIM;
  float4 xv[4];
#pragma unroll
  for (int i = 0; i < 4; ++i)
    xv[i] = *reinterpret_cast<const float4*>(xp + i * 256 + lane * 4);
#pragma unroll
  for (int i = 0; i < 4; ++i) {
    ushort4 o;
    o.x = f2bf(xv[i].x); o.y = f2bf(xv[i].y); o.z = f2bf(xv[i].z); o.w = f2bf(xv[i].w);
    *reinterpret_cast<ushort4*>(xb + (size_t)tok * DDIM + i * 256 + lane * 4) = o;
  }
  double lg[NEXP];
#pragma unroll
  for (int e = 0; e < NEXP; ++e) {
    const float* gp = gW + e * DDIM;
    double s = 0.0;
#pragma unroll
    for (int i = 0; i < 4; ++i) {
      float4 g = *reinterpret_cast<const float4*>(gp + i * 256 + lane * 4);
      s += (double)xv[i].x * g.x + (double)xv[i].y * g.y +
           (double)xv[i].z * g.z + (double)xv[i].w * g.w;
    }
    lg[e] = s;
  }
#pragma unroll
  for (int e = 0; e < NEXP; ++e)
    for (int off = 32; off > 0; off >>= 1) lg[e] += __shfl_xor(lg[e], off);
  int best = 0;
  double bv = lg[0] + (double)gb[0];
#pragma unroll
  for (int e = 1; e < NEXP; ++e) {
    double v = lg[e] + (double)gb[e];
    if (v > bv) { bv = v; best = e; }
  }
  float c[4];
#pragma unroll
  for (int r = 0; r < 4; ++r) {
    const float* ap = lA + ((size_t)best * 4 + r) * DDIM;
    float s = 0.f;
#pragma unroll
    for (int i = 0; i < 4; ++i) {
      float4 a = *reinterpret_cast<const float4*>(ap + i * 256 + lane * 4);
      s = fmaf(xv[i].x, a.x, s); s = fmaf(xv[i].y, a.y, s);
      s = fmaf(xv[i].z, a.z, s); s = fmaf(xv[i].w, a.w, s);
    }
    for (int off = 32; off > 0; off >>= 1) s += __shfl_xor(s, off);
    c[r] = s;
  }
  if (lane < 32) {
    int r = lane & 3;
    float cv = (r == 0) ? c[0] : (r == 1) ? c[1] : (r == 2) ? c[2] : c[3];
    float pv = ((lane >> 2) == best) ? cv : 0.f;
    Pmat[(size_t)tok * 32 + lane] = f2bf(pv);
  }
}

// =====================================================================
// GEMM1: inter = relu(xb @ wiWb^T + Pmat @ Bcat^T + wi_b)
// R14 quad-tile row-major structure + XOR chunk-swizzle (rule #21):
// thread (srow,sc) stages global chunk sc^swz(srow) into linear slot sc;
// reader fetches slot g^swz(row). swz(r) = (r&3)^((r>>2)&3).
// Coalescing preserved (same 64B runs per row); LDS read 8-way -> 2-way.
// swz is independent of m-step/wave-row, so read offset is lane-constant.
// =====================================================================
__global__ __launch_bounds__(256) void gemm1_kernel(
    const ushort* __restrict__ A, const ushort* __restrict__ Ap,
    const ushort* __restrict__ B, const ushort* __restrict__ Bc,
    const float* __restrict__ bias,
    const float* __restrict__ wo, ushort* __restrict__ wob,
    ushort* __restrict__ C) {
  __shared__ __align__(16) ushort lds[16384];   // 32 KB
  const int tid = threadIdx.x;
  const int lane = tid & 63;
  const int wid = tid >> 6;
  const int wr = wid >> 1, wc = wid & 1;        // 2x2 waves, each 64x64
  const int brow = blockIdx.x;                  // 64
  const int bcolg = blockIdx.y;                 // 8

  // ---- folded wo cast: this block's 8192-elem slice ----
  {
    const size_t base = (size_t)(brow * 8 + bcolg) * 8192 + tid * 8;
#pragma unroll
    for (int c = 0; c < 4; ++c) {
      const size_t off = base + c * 2048;
      float4 v0 = *reinterpret_cast<const float4*>(wo + off);
      float4 v1 = *reinterpret_cast<const float4*>(wo + off + 4);
      ushort4 o0, o1;
      o0.x = f2bf(v0.x); o0.y = f2bf(v0.y); o0.z = f2bf(v0.z); o0.w = f2bf(v0.w);
      o1.x = f2bf(v1.x); o1.y = f2bf(v1.y); o1.z = f2bf(v1.z); o1.w = f2bf(v1.w);
      *reinterpret_cast<ushort4*>(wob + off) = o0;
      *reinterpret_cast<ushort4*>(wob + off + 4) = o1;
    }
  }

  // staging ids + source chunk swizzle
  const int srow = tid >> 2;                    // 0..63
  const int sc = tid & 3;
  const int swzs = (srow & 3) ^ ((srow >> 2) & 3);
  const int scol = (sc ^ swzs) * 8;             // swizzled chunk of this row
  const ushort* gA0 = A + (size_t)(brow * 128 + srow) * DDIM + scol;
  const ushort* gA1 = A + (size_t)(brow * 128 + 64 + srow) * DDIM + scol;
  const ushort* gP0 = Ap + (size_t)(brow * 128 + srow) * 32 + scol;
  const ushort* gP1 = Ap + (size_t)(brow * 128 + 64 + srow) * 32 + scol;
  ushort* const d0 = lds + tid * 8;             // linear dest (slot sc of row srow)

  // read offsets: slot = g ^ swz(row); swz(row) depends only on rlo
  const int rlo = lane & 15;
  const int gsw = (lane >> 4) ^ ((rlo & 3) ^ ((rlo >> 2) & 3));
  const int offA = (wr * 64 + rlo) * 32 + gsw * 8;            // + m*512; k-half1 +4096
  const int offB = 8192 + (wc * 64 + rlo) * 32 + gsw * 8;
  const int ccb = wc * 64 + (lane & 15);

#pragma unroll 1
  for (int t4 = 0; t4 < 4; ++t4) {
    const int bcol = bcolg * 4 + t4;
    const ushort* gB0 = B + (size_t)(bcol * 128 + srow) * DDIM + scol;
    const ushort* gB1 = B + (size_t)(bcol * 128 + 64 + srow) * DDIM + scol;

    f32x4 acc[4][4] = {};
    __syncthreads();   // LDS safe to overwrite (prev tile's reads done)

    for (int k0 = 0; k0 < DDIM; k0 += 64) {
      gload16(gA0 + k0, d0);          gload16(gA1 + k0, d0 + 2048);
      gload16(gB0 + k0, d0 + 8192);   gload16(gB1 + k0, d0 + 8192 + 2048);
      gload16(gA0 + k0 + 32, d0 + 4096);          gload16(gA1 + k0 + 32, d0 + 4096 + 2048);
      gload16(gB0 + k0 + 32, d0 + 12288);         gload16(gB1 + k0 + 32, d0 + 12288 + 2048);
      __syncthreads();
      short8 af[4], bf[4];
#pragma unroll
      for (int m = 0; m < 4; ++m)
        af[m] = *reinterpret_cast<const short8*>(lds + offA + m * 512);
#pragma unroll
      for (int n = 0; n < 4; ++n)
        bf[n] = *reinterpret_cast<const short8*>(lds + offB + n * 512);
#pragma unroll
      for (int n = 0; n < 4; ++n)
#pragma unroll
        for (int m = 0; m < 4; ++m)
          acc[m][n] = __builtin_amdgcn_mfma_f32_16x16x32_bf16(af[m], bf[n], acc[m][n], 0, 0, 0);
#pragma unroll
      for (int m = 0; m < 4; ++m)
        af[m] = *reinterpret_cast<const short8*>(lds + 4096 + offA + m * 512);
#pragma unroll
      for (int n = 0; n < 4; ++n)
        bf[n] = *reinterpret_cast<const short8*>(lds + 4096 + offB + n * 512);
#pragma unroll
      for (int n = 0; n < 4; ++n)
#pragma unroll
        for (int m = 0; m < 4; ++m)
          acc[m][n] = __builtin_amdgcn_mfma_f32_16x16x32_bf16(af[m], bf[n], acc[m][n], 0, 0, 0);
      __syncthreads();
    }

    // ---- lora fold: BK=32 over P [8192][32] x Bcat [4096][32] ----
    {
      const ushort* gQ0 = Bc + (size_t)(bcol * 128 + srow) * 32 + scol;
      const ushort* gQ1 = Bc + (size_t)(bcol * 128 + 64 + srow) * 32 + scol;
      gload16(gP0, d0);          gload16(gP1, d0 + 2048);
      gload16(gQ0, d0 + 8192);   gload16(gQ1, d0 + 8192 + 2048);
      __syncthreads();
      short8 af[4], bf[4];
#pragma unroll
      for (int m = 0; m < 4; ++m)
        af[m] = *reinterpret_cast<const short8*>(lds + offA + m * 512);
#pragma unroll
      for (int n = 0; n < 4; ++n)
        bf[n] = *reinterpret_cast<const short8*>(lds + offB + n * 512);
#pragma unroll
      for (int n = 0; n < 4; ++n)
#pragma unroll
        for (int m = 0; m < 4; ++m)
          acc[m][n] = __builtin_amdgcn_mfma_f32_16x16x32_bf16(af[m], bf[n], acc[m][n], 0, 0, 0);
    }

    // ---- epilogue: bias + relu + bf16 store ----
    float bias4[4];
#pragma unroll
    for (int fn = 0; fn < 4; ++fn) bias4[fn] = bias[bcol * 128 + ccb + fn * 16];
#pragma unroll
    for (int fm = 0; fm < 4; ++fm) {
#pragma unroll
      for (int q = 0; q < 4; ++q) {
        const int tl = wr * 64 + fm * 16 + ((lane >> 4) << 2) + q;
        ushort* crow = C + (size_t)(brow * 128 + tl) * FDIM + bcol * 128;
#pragma unroll
        for (int fn = 0; fn < 4; ++fn) {
          float v = acc[fm][fn][q] + bias4[fn];
          crow[ccb + fn * 16] = f2bf(fmaxf(v, 0.f));
        }
      }
    }
  }
}

// =====================================================================
// GEMM2 (round-10 proven, ~69us): out = inter @ woWb^T + wo_b  (f32)
// m97 128x128 + BK=64 unroll-by-2. UNCHANGED.
// =====================================================================
__global__ __launch_bounds__(256) void gemm2_kernel(
    const ushort* __restrict__ A, const ushort* __restrict__ B,
    const float* __restrict__ bias, float* __restrict__ C) {
  __shared__ __align__(16) ushort lds[16384];   // 32 KB
  const int tid = threadIdx.x;
  const int lane = tid & 63;
  const int wid = tid >> 6;
  const int wr = wid >> 1, wc = wid & 1;
  const int brow = blockIdx.x, bcol = blockIdx.y;

  f32x4 acc[4][4] = {};

  const int srow = tid >> 2;
  const int scol = (tid & 3) * 8;
  const ushort* gA0 = A + (size_t)(brow * 128 + srow) * FDIM + scol;
  const ushort* gA1 = A + (size_t)(brow * 128 + 64 + srow) * FDIM + scol;
  const ushort* gB0 = B + (size_t)(bcol * 128 + srow) * FDIM + scol;
  const ushort* gB1 = B + (size_t)(bcol * 128 + 64 + srow) * FDIM + scol;
  ushort* const d0 = lds + tid * 8;

  const int offA = (wr * 64 + (lane & 15)) * 32 + (lane >> 4) * 8;
  const int offB = 8192 + (wc * 64 + (lane & 15)) * 32 + (lane >> 4) * 8;

  for (int k0 = 0; k0 < FDIM; k0 += 64) {
    gload16(gA0 + k0, d0);          gload16(gA1 + k0, d0 + 2048);
    gload16(gB0 + k0, d0 + 8192);   gload16(gB1 + k0, d0 + 8192 + 2048);
    gload16(gA0 + k0 + 32, d0 + 4096);          gload16(gA1 + k0 + 32, d0 + 4096 + 2048);
    gload16(gB0 + k0 + 32, d0 + 12288);         gload16(gB1 + k0 + 32, d0 + 12288 + 2048);
    __syncthreads();
    short8 af[4], bf[4];
#pragma unroll
    for (int m = 0; m < 4; ++m)
      af[m] = *reinterpret_cast<const short8*>(lds + offA + m * 512);
#pragma unroll
    for (int n = 0; n < 4; ++n)
      bf[n] = *reinterpret_cast<const short8*>(lds + offB + n * 512);
#pragma unroll
    for (int n = 0; n < 4; ++n)
#pragma unroll
      for (int m = 0; m < 4; ++m)
        acc[m][n] = __builtin_amdgcn_mfma_f32_16x16x32_bf16(af[m], bf[n], acc[m][n], 0, 0, 0);
#pragma unroll
    for (int m = 0; m < 4; ++m)
      af[m] = *reinterpret_cast<const short8*>(lds + 4096 + offA + m * 512);
#pragma unroll
    for (int n = 0; n < 4; ++n)
      bf[n] = *reinterpret_cast<const short8*>(lds + 4096 + offB + n * 512);
#pragma unroll
    for (int n = 0; n < 4; ++n)
#pragma unroll
      for (int m = 0; m < 4; ++m)
        acc[m][n] = __builtin_amdgcn_mfma_f32_16x16x32_bf16(af[m], bf[n], acc[m][n], 0, 0, 0);
    __syncthreads();
  }

  const int dbase = bcol * 128 + wc * 64 + (lane & 15);
  const int tokbase = brow * 128 + wr * 64 + ((lane >> 4) << 2);
  float bias4[4];
#pragma unroll
  for (int n = 0; n < 4; ++n) bias4[n] = bias[dbase + n * 16];
#pragma unroll
  for (int m = 0; m < 4; ++m) {
#pragma unroll
    for (int q = 0; q < 4; ++q) {
      const int tok = tokbase + m * 16 + q;
#pragma unroll
      for (int n = 0; n < 4; ++n)
        C[(size_t)tok * DDIM + dbase + n * 16] = acc[m][n][q] + bias4[n];
    }
  }
}

extern "C" void kernel_launch(void* const* d_in, const int* in_sizes, int n_in,
                              void* d_out, int out_size, void* d_ws, size_t ws_size,
                              hipStream_t stream) {
  const float* x      = (const float*)d_in[0];
  const float* gate_W = (const float*)d_in[1];
  const float* gate_b = (const float*)d_in[2];
  const float* wi_W   = (const float*)d_in[3];
  const float* wi_b   = (const float*)d_in[4];
  const float* wo_W   = (const float*)d_in[5];
  const float* wo_b   = (const float*)d_in[6];
  const float* lora_A = (const float*)d_in[7];
  const float* lora_B = (const float*)d_in[8];
  float* out = (float*)d_out;

  char* ws = (char*)d_ws;
  ushort* xb    = (ushort*)(ws);                       // 16.78 MB
  ushort* wiWb  = (ushort*)(ws + 16777216);            //  8.39 MB
  ushort* woWb  = (ushort*)(ws + 25165824);            //  8.39 MB
  ushort* inter = (ushort*)(ws + 33554432);            // 67.1  MB
  ushort* Pmat  = (ushort*)(ws + 100663296);           // 512 KB
  ushort* BcatB = (ushort*)(ws + 101187584);           // 256 KB

  prep_kernel<<<6144, 256, 0, stream>>>(wi_W, wiWb,
                                        x, gate_W, gate_b, lora_A, lora_B,
                                        Pmat, BcatB, xb);
  gemm1_kernel<<<dim3(64, 8), 256, 0, stream>>>(
      xb, Pmat, wiWb, BcatB, wi_b, wo_W, woWb, inter);
  gemm2_kernel<<<dim3(N_TOK / 128, DDIM / 128), 256, 0, stream>>>(inter, woWb, wo_b, out);
}

// Round 18
// 190.076 us; speedup vs baseline: 1.2992x; 1.0033x over previous
//
#include <hip/hip_runtime.h>
#include <hip/hip_bf16.h>
#include <stdint.h>

#define N_TOK 8192
#define DDIM 1024
#define FDIM 4096
#define NEXP 8

typedef __attribute__((ext_vector_type(8))) short short8;
typedef __attribute__((ext_vector_type(4))) float f32x4;

__device__ __forceinline__ ushort f2bf(float f) {
  uint32_t u = __float_as_uint(f);
  u += 0x7FFF + ((u >> 16) & 1);   // RNE
  return (ushort)(u >> 16);
}

__device__ __forceinline__ void gload16(const void* g, void* l) {
  __builtin_amdgcn_global_load_lds((const __attribute__((address_space(1))) void*)g,
                                   (__attribute__((address_space(3))) void*)l, 16, 0, 0);
}

// ---------- prep (R13 proven) ----------
__global__ __launch_bounds__(256) void prep_kernel(
    const float* __restrict__ wi, ushort* __restrict__ wib,
    const float* __restrict__ x, const float* __restrict__ gW, const float* __restrict__ gb,
    const float* __restrict__ lA, const float* __restrict__ lB,
    ushort* __restrict__ Pmat, ushort* __restrict__ BcatB,
    ushort* __restrict__ xb) {
  if (blockIdx.x < 4096) {
    int i = blockIdx.x * 256 + threadIdx.x;
    float4 v = reinterpret_cast<const float4*>(wi)[i];
    ushort4 o;
    o.x = f2bf(v.x); o.y = f2bf(v.y); o.z = f2bf(v.z); o.w = f2bf(v.w);
    reinterpret_cast<ushort4*>(wib)[i] = o;
    return;
  }
  const int rblk = blockIdx.x - 4096;              // [0, 2048)
  if (threadIdx.x < 16) {
    int idx = rblk * 64 + threadIdx.x * 4;
    int f = idx >> 5;
    int e = (idx & 31) >> 2;
    const float* src = lB + ((size_t)e * FDIM + f) * 4;
    ushort4 o;
    o.x = f2bf(src[0]); o.y = f2bf(src[1]); o.z = f2bf(src[2]); o.w = f2bf(src[3]);
    *reinterpret_cast<ushort4*>(BcatB + idx) = o;
  }
  const int lane = threadIdx.x & 63;
  const int wid = threadIdx.x >> 6;
  const int tok = rblk * 4 + wid;
  const float* xp = x + (size_t)tok * DDIM;
  float4 xv[4];
#pragma unroll
  for (int i = 0; i < 4; ++i)
    xv[i] = *reinterpret_cast<const float4*>(xp + i * 256 + lane * 4);
#pragma unroll
  for (int i = 0; i < 4; ++i) {
    ushort4 o;
    o.x = f2bf(xv[i].x); o.y = f2bf(xv[i].y); o.z = f2bf(xv[i].z); o.w = f2bf(xv[i].w);
    *reinterpret_cast<ushort4*>(xb + (size_t)tok * DDIM + i * 256 + lane * 4) = o;
  }
  double lg[NEXP];
#pragma unroll
  for (int e = 0; e < NEXP; ++e) {
    const float* gp = gW + e * DDIM;
    double s = 0.0;
#pragma unroll
    for (int i = 0; i < 4; ++i) {
      float4 g = *reinterpret_cast<const float4*>(gp + i * 256 + lane * 4);
      s += (double)xv[i].x * g.x + (double)xv[i].y * g.y +
           (double)xv[i].z * g.z + (double)xv[i].w * g.w;
    }
    lg[e] = s;
  }
#pragma unroll
  for (int e = 0; e < NEXP; ++e)
    for (int off = 32; off > 0; off >>= 1) lg[e] += __shfl_xor(lg[e], off);
  int best = 0;
  double bv = lg[0] + (double)gb[0];
#pragma unroll
  for (int e = 1; e < NEXP; ++e) {
    double v = lg[e] + (double)gb[e];
    if (v > bv) { bv = v; best = e; }
  }
  float c[4];
#pragma unroll
  for (int r = 0; r < 4; ++r) {
    const float* ap = lA + ((size_t)best * 4 + r) * DDIM;
    float s = 0.f;
#pragma unroll
    for (int i = 0; i < 4; ++i) {
      float4 a = *reinterpret_cast<const float4*>(ap + i * 256 + lane * 4);
      s = fmaf(xv[i].x, a.x, s); s = fmaf(xv[i].y, a.y, s);
      s = fmaf(xv[i].z, a.z, s); s = fmaf(xv[i].w, a.w, s);
    }
    for (int off = 32; off > 0; off >>= 1) s += __shfl_xor(s, off);
    c[r] = s;
  }
  if (lane < 32) {
    int r = lane & 3;
    float cv = (r == 0) ? c[0] : (r == 1) ? c[1] : (r == 2) ? c[2] : c[3];
    float pv = ((lane >> 2) == best) ? cv : 0.f;
    Pmat[(size_t)tok * 32 + lane] = f2bf(pv);
  }
}

// =====================================================================
// GEMM1: inter = relu(xb @ wiWb^T + Pmat @ Bcat^T + wi_b)
// R14 quad-tile row-major structure + XOR chunk-swizzle (neutral but
// verified-correct). BK=64 (the deterministic, 5x-validated config).
// =====================================================================
__global__ __launch_bounds__(256) void gemm1_kernel(
    const ushort* __restrict__ A, const ushort* __restrict__ Ap,
    const ushort* __restrict__ B, const ushort* __restrict__ Bc,
    const float* __restrict__ bias,
    const float* __restrict__ wo, ushort* __restrict__ wob,
    ushort* __restrict__ C) {
  __shared__ __align__(16) ushort lds[16384];   // 32 KB
  const int tid = threadIdx.x;
  const int lane = tid & 63;
  const int wid = tid >> 6;
  const int wr = wid >> 1, wc = wid & 1;        // 2x2 waves, each 64x64
  const int brow = blockIdx.x;                  // 64
  const int bcolg = blockIdx.y;                 // 8

  // ---- folded wo cast: this block's 8192-elem slice ----
  {
    const size_t base = (size_t)(brow * 8 + bcolg) * 8192 + tid * 8;
#pragma unroll
    for (int c = 0; c < 4; ++c) {
      const size_t off = base + c * 2048;
      float4 v0 = *reinterpret_cast<const float4*>(wo + off);
      float4 v1 = *reinterpret_cast<const float4*>(wo + off + 4);
      ushort4 o0, o1;
      o0.x = f2bf(v0.x); o0.y = f2bf(v0.y); o0.z = f2bf(v0.z); o0.w = f2bf(v0.w);
      o1.x = f2bf(v1.x); o1.y = f2bf(v1.y); o1.z = f2bf(v1.z); o1.w = f2bf(v1.w);
      *reinterpret_cast<ushort4*>(wob + off) = o0;
      *reinterpret_cast<ushort4*>(wob + off + 4) = o1;
    }
  }

  // staging ids + source chunk swizzle
  const int srow = tid >> 2;                    // 0..63
  const int sc = tid & 3;
  const int swzs = (srow & 3) ^ ((srow >> 2) & 3);
  const int scol = (sc ^ swzs) * 8;             // swizzled chunk of this row
  const ushort* gA0 = A + (size_t)(brow * 128 + srow) * DDIM + scol;
  const ushort* gA1 = A + (size_t)(brow * 128 + 64 + srow) * DDIM + scol;
  const ushort* gP0 = Ap + (size_t)(brow * 128 + srow) * 32 + scol;
  const ushort* gP1 = Ap + (size_t)(brow * 128 + 64 + srow) * 32 + scol;
  ushort* const d0 = lds + tid * 8;             // linear dest (slot sc of row srow)

  // read offsets: slot = g ^ swz(row); swz(row) depends only on rlo
  const int rlo = lane & 15;
  const int gsw = (lane >> 4) ^ ((rlo & 3) ^ ((rlo >> 2) & 3));
  const int offA = (wr * 64 + rlo) * 32 + gsw * 8;            // + m*512; k-half1 +4096
  const int offB = 8192 + (wc * 64 + rlo) * 32 + gsw * 8;
  const int ccb = wc * 64 + (lane & 15);

#pragma unroll 1
  for (int t4 = 0; t4 < 4; ++t4) {
    const int bcol = bcolg * 4 + t4;
    const ushort* gB0 = B + (size_t)(bcol * 128 + srow) * DDIM + scol;
    const ushort* gB1 = B + (size_t)(bcol * 128 + 64 + srow) * DDIM + scol;

    f32x4 acc[4][4] = {};
    __syncthreads();   // LDS safe to overwrite (prev tile's reads done)

    for (int k0 = 0; k0 < DDIM; k0 += 64) {
      gload16(gA0 + k0, d0);          gload16(gA1 + k0, d0 + 2048);
      gload16(gB0 + k0, d0 + 8192);   gload16(gB1 + k0, d0 + 8192 + 2048);
      gload16(gA0 + k0 + 32, d0 + 4096);          gload16(gA1 + k0 + 32, d0 + 4096 + 2048);
      gload16(gB0 + k0 + 32, d0 + 12288);         gload16(gB1 + k0 + 32, d0 + 12288 + 2048);
      __syncthreads();
      short8 af[4], bf[4];
#pragma unroll
      for (int m = 0; m < 4; ++m)
        af[m] = *reinterpret_cast<const short8*>(lds + offA + m * 512);
#pragma unroll
      for (int n = 0; n < 4; ++n)
        bf[n] = *reinterpret_cast<const short8*>(lds + offB + n * 512);
#pragma unroll
      for (int n = 0; n < 4; ++n)
#pragma unroll
        for (int m = 0; m < 4; ++m)
          acc[m][n] = __builtin_amdgcn_mfma_f32_16x16x32_bf16(af[m], bf[n], acc[m][n], 0, 0, 0);
#pragma unroll
      for (int m = 0; m < 4; ++m)
        af[m] = *reinterpret_cast<const short8*>(lds + 4096 + offA + m * 512);
#pragma unroll
      for (int n = 0; n < 4; ++n)
        bf[n] = *reinterpret_cast<const short8*>(lds + 4096 + offB + n * 512);
#pragma unroll
      for (int n = 0; n < 4; ++n)
#pragma unroll
        for (int m = 0; m < 4; ++m)
          acc[m][n] = __builtin_amdgcn_mfma_f32_16x16x32_bf16(af[m], bf[n], acc[m][n], 0, 0, 0);
      __syncthreads();
    }

    // ---- lora fold: BK=32 over P [8192][32] x Bcat [4096][32] ----
    {
      const ushort* gQ0 = Bc + (size_t)(bcol * 128 + srow) * 32 + scol;
      const ushort* gQ1 = Bc + (size_t)(bcol * 128 + 64 + srow) * 32 + scol;
      gload16(gP0, d0);          gload16(gP1, d0 + 2048);
      gload16(gQ0, d0 + 8192);   gload16(gQ1, d0 + 8192 + 2048);
      __syncthreads();
      short8 af[4], bf[4];
#pragma unroll
      for (int m = 0; m < 4; ++m)
        af[m] = *reinterpret_cast<const short8*>(lds + offA + m * 512);
#pragma unroll
      for (int n = 0; n < 4; ++n)
        bf[n] = *reinterpret_cast<const short8*>(lds + offB + n * 512);
#pragma unroll
      for (int n = 0; n < 4; ++n)
#pragma unroll
        for (int m = 0; m < 4; ++m)
          acc[m][n] = __builtin_amdgcn_mfma_f32_16x16x32_bf16(af[m], bf[n], acc[m][n], 0, 0, 0);
    }

    // ---- epilogue: bias + relu + bf16 store ----
    float bias4[4];
#pragma unroll
    for (int fn = 0; fn < 4; ++fn) bias4[fn] = bias[bcol * 128 + ccb + fn * 16];
#pragma unroll
    for (int fm = 0; fm < 4; ++fm) {
#pragma unroll
      for (int q = 0; q < 4; ++q) {
        const int tl = wr * 64 + fm * 16 + ((lane >> 4) << 2) + q;
        ushort* crow = C + (size_t)(brow * 128 + tl) * FDIM + bcol * 128;
#pragma unroll
        for (int fn = 0; fn < 4; ++fn) {
          float v = acc[fm][fn][q] + bias4[fn];
          crow[ccb + fn * 16] = f2bf(fmaxf(v, 0.f));
        }
      }
    }
  }
}

// =====================================================================
// GEMM2 (round-10 proven, ~69us): out = inter @ woWb^T + wo_b  (f32)
// m97 128x128 + BK=64 unroll-by-2. UNCHANGED.
// =====================================================================
__global__ __launch_bounds__(256) void gemm2_kernel(
    const ushort* __restrict__ A, const ushort* __restrict__ B,
    const float* __restrict__ bias, float* __restrict__ C) {
  __shared__ __align__(16) ushort lds[16384];   // 32 KB
  const int tid = threadIdx.x;
  const int lane = tid & 63;
  const int wid = tid >> 6;
  const int wr = wid >> 1, wc = wid & 1;
  const int brow = blockIdx.x, bcol = blockIdx.y;

  f32x4 acc[4][4] = {};

  const int srow = tid >> 2;
  const int scol = (tid & 3) * 8;
  const ushort* gA0 = A + (size_t)(brow * 128 + srow) * FDIM + scol;
  const ushort* gA1 = A + (size_t)(brow * 128 + 64 + srow) * FDIM + scol;
  const ushort* gB0 = B + (size_t)(bcol * 128 + srow) * FDIM + scol;
  const ushort* gB1 = B + (size_t)(bcol * 128 + 64 + srow) * FDIM + scol;
  ushort* const d0 = lds + tid * 8;

  const int offA = (wr * 64 + (lane & 15)) * 32 + (lane >> 4) * 8;
  const int offB = 8192 + (wc * 64 + (lane & 15)) * 32 + (lane >> 4) * 8;

  for (int k0 = 0; k0 < FDIM; k0 += 64) {
    gload16(gA0 + k0, d0);          gload16(gA1 + k0, d0 + 2048);
    gload16(gB0 + k0, d0 + 8192);   gload16(gB1 + k0, d0 + 8192 + 2048);
    gload16(gA0 + k0 + 32, d0 + 4096);          gload16(gA1 + k0 + 32, d0 + 4096 + 2048);
    gload16(gB0 + k0 + 32, d0 + 12288);         gload16(gB1 + k0 + 32, d0 + 12288 + 2048);
    __syncthreads();
    short8 af[4], bf[4];
#pragma unroll
    for (int m = 0; m < 4; ++m)
      af[m] = *reinterpret_cast<const short8*>(lds + offA + m * 512);
#pragma unroll
    for (int n = 0; n < 4; ++n)
      bf[n] = *reinterpret_cast<const short8*>(lds + offB + n * 512);
#pragma unroll
    for (int n = 0; n < 4; ++n)
#pragma unroll
      for (int m = 0; m < 4; ++m)
        acc[m][n] = __builtin_amdgcn_mfma_f32_16x16x32_bf16(af[m], bf[n], acc[m][n], 0, 0, 0);
#pragma unroll
    for (int m = 0; m < 4; ++m)
      af[m] = *reinterpret_cast<const short8*>(lds + 4096 + offA + m * 512);
#pragma unroll
    for (int n = 0; n < 4; ++n)
      bf[n] = *reinterpret_cast<const short8*>(lds + 4096 + offB + n * 512);
#pragma unroll
    for (int n = 0; n < 4; ++n)
#pragma unroll
      for (int m = 0; m < 4; ++m)
        acc[m][n] = __builtin_amdgcn_mfma_f32_16x16x32_bf16(af[m], bf[n], acc[m][n], 0, 0, 0);
    __syncthreads();
  }

  const int dbase = bcol * 128 + wc * 64 + (lane & 15);
  const int tokbase = brow * 128 + wr * 64 + ((lane >> 4) << 2);
  float bias4[4];
#pragma unroll
  for (int n = 0; n < 4; ++n) bias4[n] = bias[dbase + n * 16];
#pragma unroll
  for (int m = 0; m < 4; ++m) {
#pragma unroll
    for (int q = 0; q < 4; ++q) {
      const int tok = tokbase + m * 16 + q;
#pragma unroll
      for (int n = 0; n < 4; ++n)
        C[(size_t)tok * DDIM + dbase + n * 16] = acc[m][n][q] + bias4[n];
    }
  }
}

extern "C" void kernel_launch(void* const* d_in, const int* in_sizes, int n_in,
                              void* d_out, int out_size, void* d_ws, size_t ws_size,
                              hipStream_t stream) {
  const float* x      = (const float*)d_in[0];
  const float* gate_W = (const float*)d_in[1];
  const float* gate_b = (const float*)d_in[2];
  const float* wi_W   = (const float*)d_in[3];
  const float* wi_b   = (const float*)d_in[4];
  const float* wo_W   = (const float*)d_in[5];
  const float* wo_b   = (const float*)d_in[6];
  const float* lora_A = (const float*)d_in[7];
  const float* lora_B = (const float*)d_in[8];
  float* out = (float*)d_out;

  char* ws = (char*)d_ws;
  ushort* xb    = (ushort*)(ws);                       // 16.78 MB
  ushort* wiWb  = (ushort*)(ws + 16777216);            //  8.39 MB
  ushort* woWb  = (ushort*)(ws + 25165824);            //  8.39 MB
  ushort* inter = (ushort*)(ws + 33554432);            // 67.1  MB
  ushort* Pmat  = (ushort*)(ws + 100663296);           // 512 KB
  ushort* BcatB = (ushort*)(ws + 101187584);           // 256 KB

  prep_kernel<<<6144, 256, 0, stream>>>(wi_W, wiWb,
                                        x, gate_W, gate_b, lora_A, lora_B,
                                        Pmat, BcatB, xb);
  gemm1_kernel<<<dim3(64, 8), 256, 0, stream>>>(
      xb, Pmat, wiWb, BcatB, wi_b, wo_W, woWb, inter);
  gemm2_kernel<<<dim3(N_TOK / 128, DDIM / 128), 256, 0, stream>>>(inter, woWb, wo_b, out);
}